// Round 1
// baseline (1481.843 us; speedup 1.0000x reference)
//
#include <hip/hip_runtime.h>
#include <hip/hip_bf16.h>

#define BATCH 8192
#define IN_DIM 64
#define HID 1024
#define KTOT 1088   // HID + IN_DIM, fused K
#define NGATES 4096 // 4*HID
#define OMID 128
#define NP 256      // padded mid cols (W1 rows 0..127, W_halt row 128, zeros)
#define MAX_ITER 8

#define TM 128
#define TN 128
#define TK 64

typedef __attribute__((ext_vector_type(8))) short short8;
typedef __attribute__((ext_vector_type(4))) float float4v;

__device__ __forceinline__ float bf2f(short s) {
    union { float f; unsigned u; } v; v.u = ((unsigned)(unsigned short)s) << 16; return v.f;
}
__device__ __forceinline__ short f2bf(float f) {
    union { float f; unsigned u; } v; v.f = f;
    unsigned r = v.u + 0x7fff + ((v.u >> 16) & 1);  // round-to-nearest-even
    return (short)(r >> 16);
}
__device__ __forceinline__ float sigmoidf_(float x) {
    float xc = fminf(fmaxf(x, -30.f), 30.f);
    return 1.f / (1.f + __expf(-xc));
}
__device__ __forceinline__ float tanhf_(float x) {
    float xc = fminf(fmaxf(x, -15.f), 15.f);
    float e = __expf(2.f * xc);
    return (e - 1.f) / (e + 1.f);
}

// C[M][N] = act( A[M][K] * B[N][K]^T + bias[N] )
// mode 0: gates -> bf16 out, sigmoid except tanh for gate 2 (cols 2048..3071)
// mode 1: mid   -> fp32 out, relu for col<128, sigmoid for col==128, 0 else
__global__ __launch_bounds__(256) void gemm_act(
    const short* __restrict__ A, int lda,
    const short* __restrict__ B, int ldb,
    const float* __restrict__ bias,
    void* __restrict__ Cout, int ldc,
    int K, int mode)
{
    __shared__ short As[TM * TK];
    __shared__ short Bs[TN * TK];
    const int tid  = threadIdx.x;
    const int wave = tid >> 6, lane = tid & 63;
    const int n0 = blockIdx.x * TN;
    const int m0 = blockIdx.y * TM;
    const int wm = wave & 1, wn = wave >> 1;

    float4v acc[4][4];
#pragma unroll
    for (int i = 0; i < 4; ++i)
#pragma unroll
        for (int j = 0; j < 4; ++j) acc[i][j] = (float4v)0.f;

    const int lrow8 = lane >> 3;        // 0..7 (row within 8-row region)
    const int lk    = (lane & 7) * 8;   // k element offset 0..56

    for (int k0 = 0; k0 < K; k0 += TK) {
#pragma unroll
        for (int it = 0; it < 4; ++it) {
            const int rr = (wave * 4 + it) * 8;   // wave-uniform region row base
            const short* ga = A + (size_t)(m0 + rr + lrow8) * lda + k0 + lk;
            __builtin_amdgcn_global_load_lds(
                (const __attribute__((address_space(1))) void*)ga,
                (__attribute__((address_space(3))) void*)(As + rr * TK), 16, 0, 0);
            const short* gb = B + (size_t)(n0 + rr + lrow8) * ldb + k0 + lk;
            __builtin_amdgcn_global_load_lds(
                (const __attribute__((address_space(1))) void*)gb,
                (__attribute__((address_space(3))) void*)(Bs + rr * TK), 16, 0, 0);
        }
        __syncthreads();
#pragma unroll
        for (int kk = 0; kk < TK; kk += 32) {
            short8 af[4], bf[4];
#pragma unroll
            for (int i = 0; i < 4; ++i) {
                af[i] = *(const short8*)(As + (wm * 64 + i * 16 + (lane & 15)) * TK + kk + (lane >> 4) * 8);
                bf[i] = *(const short8*)(Bs + (wn * 64 + i * 16 + (lane & 15)) * TK + kk + (lane >> 4) * 8);
            }
#pragma unroll
            for (int i = 0; i < 4; ++i)
#pragma unroll
                for (int j = 0; j < 4; ++j)
                    acc[i][j] = __builtin_amdgcn_mfma_f32_16x16x32_bf16(af[i], bf[j], acc[i][j], 0, 0, 0);
        }
        __syncthreads();
    }

    const int colq = lane & 15;
    const int rowq = (lane >> 4) * 4;
    if (mode == 0) {
        short* C = (short*)Cout;
#pragma unroll
        for (int i = 0; i < 4; ++i) {
            const int rbase = m0 + wm * 64 + i * 16 + rowq;
#pragma unroll
            for (int j = 0; j < 4; ++j) {
                const int col = n0 + wn * 64 + j * 16 + colq;
                const float b = bias[col];
                const bool is_tanh = ((col >> 10) == 2);
#pragma unroll
                for (int r = 0; r < 4; ++r) {
                    float v = acc[i][j][r] + b;
                    v = is_tanh ? tanhf_(v) : sigmoidf_(v);
                    C[(size_t)(rbase + r) * ldc + col] = f2bf(v);
                }
            }
        }
    } else {
        float* C = (float*)Cout;
#pragma unroll
        for (int i = 0; i < 4; ++i) {
            const int rbase = m0 + wm * 64 + i * 16 + rowq;
#pragma unroll
            for (int j = 0; j < 4; ++j) {
                const int col = n0 + wn * 64 + j * 16 + colq;
                const float b = bias[col];
#pragma unroll
                for (int r = 0; r < 4; ++r) {
                    float v = acc[i][j][r] + b;
                    if (col < OMID) v = fmaxf(v, 0.f);
                    else if (col == OMID) v = sigmoidf_(v);
                    else v = 0.f;
                    C[(size_t)(rbase + r) * ldc + col] = v;
                }
            }
        }
    }
}

// cell = f*cell + i*c ; state = o*tanh(cell)  (active rows only)
__global__ __launch_bounds__(256) void cell_update(
    const short* __restrict__ gates, float* __restrict__ cell,
    short* __restrict__ A, const int* __restrict__ active)
{
    const int idx = blockIdx.x * 256 + threadIdx.x;  // over BATCH*HID
    const int row = idx >> 10, h = idx & 1023;
    if (!active[row]) return;
    const size_t gb = (size_t)row * NGATES + h;
    const float ig = bf2f(gates[gb]);
    const float fg = bf2f(gates[gb + 1024]);
    const float cg = bf2f(gates[gb + 2048]);
    const float og = bf2f(gates[gb + 3072]);
    const float c = fg * cell[idx] + ig * cg;
    cell[idx] = c;
    A[(size_t)row * KTOT + h] = f2bf(og * tanhf_(c));
}

// one wave per row: out = sigmoid(mid[0:128]·W2 + b2); halting bookkeeping
__global__ __launch_bounds__(256) void finalize_k(
    const float* __restrict__ mid, const float* __restrict__ W2, const float* __restrict__ b2,
    float* __restrict__ outp, float* __restrict__ p_sum, int* __restrict__ active, int t)
{
    const int wave = threadIdx.x >> 6, lane = threadIdx.x & 63;
    const int row = blockIdx.x * 4 + wave;
    if (!active[row]) return;
    const float* m = mid + (size_t)row * NP;
    float v = m[lane] * W2[lane] + m[lane + 64] * W2[lane + 64];
#pragma unroll
    for (int o = 32; o > 0; o >>= 1) v += __shfl_down(v, o);
    if (lane == 0) {
        const float ov = sigmoidf_(v + b2[0]);
        const float h  = m[OMID];
        const float p  = p_sum[row];
        const float pn = p + h;
        const bool fin = (pn >= 1.f - 1e-3f) || (t == MAX_ITER - 1);
        const float halt = fin ? (1.f - p) : h;
        outp[row] += ov * halt;
        p_sum[row] = fin ? 1.f : pn;
        if (fin) active[row] = 0;
    }
}

__global__ __launch_bounds__(256) void pack_gates(
    const float* __restrict__ Whi, const float* __restrict__ Whf,
    const float* __restrict__ Whc, const float* __restrict__ Who,
    const float* __restrict__ Wxi, const float* __restrict__ Wxf,
    const float* __restrict__ Wxc, const float* __restrict__ Wxo,
    const float* __restrict__ bxi, const float* __restrict__ bhi,
    const float* __restrict__ bxf, const float* __restrict__ bhf,
    const float* __restrict__ bxc, const float* __restrict__ bhc,
    const float* __restrict__ bxo, const float* __restrict__ bho,
    short* __restrict__ Wg, float* __restrict__ bias_g)
{
    const int idx = blockIdx.x * 256 + threadIdx.x;  // over NGATES*KTOT
    if (idx >= NGATES * KTOT) return;
    const int n = idx / KTOT, k = idx - n * KTOT;
    const int g = n >> 10, h = n & 1023;
    const float* Wh = (g == 0) ? Whi : (g == 1) ? Whf : (g == 2) ? Whc : Who;
    const float* Wx = (g == 0) ? Wxi : (g == 1) ? Wxf : (g == 2) ? Wxc : Wxo;
    const float v = (k < HID) ? Wh[h * HID + k] : Wx[h * IN_DIM + (k - HID)];
    Wg[idx] = f2bf(v);
    if (k == 0) {
        const float* bx = (g == 0) ? bxi : (g == 1) ? bxf : (g == 2) ? bxc : bxo;
        const float* bh = (g == 0) ? bhi : (g == 1) ? bhf : (g == 2) ? bhc : bho;
        bias_g[n] = bx[h] + bh[h];
    }
}

__global__ __launch_bounds__(256) void pack_P(
    const float* __restrict__ W1, const float* __restrict__ b1,
    const float* __restrict__ W_halt, const float* __restrict__ b_halt,
    short* __restrict__ P, float* __restrict__ bias_p)
{
    const int idx = blockIdx.x * 256 + threadIdx.x;  // over NP*HID
    if (idx >= NP * HID) return;
    const int n = idx >> 10, k = idx & 1023;
    const float v = (n < OMID) ? W1[n * HID + k] : (n == OMID ? W_halt[k] : 0.f);
    P[idx] = f2bf(v);
    if (k == 0) bias_p[n] = (n < OMID) ? b1[n] : (n == OMID ? b_halt[0] : 0.f);
}

__global__ __launch_bounds__(256) void init_k(
    const float* __restrict__ x, short* __restrict__ A, float* __restrict__ cell,
    float* __restrict__ p_sum, int* __restrict__ active, float* __restrict__ outp)
{
    const int idx = blockIdx.x * 256 + threadIdx.x;  // over BATCH*KTOT
    if (idx >= BATCH * KTOT) return;
    const int row = idx / KTOT, k = idx - row * KTOT;
    A[idx] = (k < HID) ? (short)0 : f2bf(x[row * IN_DIM + (k - HID)]);
    if (k < HID) cell[(size_t)row * HID + k] = 0.f;
    if (k == 0) { p_sum[row] = 0.f; active[row] = 1; outp[row] = 0.f; }
}

extern "C" void kernel_launch(void* const* d_in, const int* in_sizes, int n_in,
                              void* d_out, int out_size, void* d_ws, size_t ws_size,
                              hipStream_t stream) {
    const float* x    = (const float*)d_in[0];
    const float* Wxi  = (const float*)d_in[1];
    const float* bxi  = (const float*)d_in[2];
    const float* Whi  = (const float*)d_in[3];
    const float* bhi  = (const float*)d_in[4];
    const float* Wxf  = (const float*)d_in[5];
    const float* bxf  = (const float*)d_in[6];
    const float* Whf  = (const float*)d_in[7];
    const float* bhf  = (const float*)d_in[8];
    const float* Wxc  = (const float*)d_in[9];
    const float* bxc  = (const float*)d_in[10];
    const float* Whc  = (const float*)d_in[11];
    const float* bhc  = (const float*)d_in[12];
    const float* Wxo  = (const float*)d_in[13];
    const float* bxo  = (const float*)d_in[14];
    const float* Who  = (const float*)d_in[15];
    const float* bho  = (const float*)d_in[16];
    const float* W_halt = (const float*)d_in[17];
    const float* b_halt = (const float*)d_in[18];
    const float* W1   = (const float*)d_in[19];
    const float* b1   = (const float*)d_in[20];
    const float* W2   = (const float*)d_in[21];
    const float* b2   = (const float*)d_in[22];

    char* p = (char*)d_ws;
    auto carve = [&](size_t bytes) { char* r = p; p += (bytes + 255) & ~(size_t)255; return r; };
    short* A      = (short*)carve((size_t)BATCH * KTOT * 2);
    short* Wg     = (short*)carve((size_t)NGATES * KTOT * 2);
    float* bias_g = (float*)carve((size_t)NGATES * 4);
    short* P      = (short*)carve((size_t)NP * HID * 2);
    float* bias_p = (float*)carve((size_t)NP * 4);
    short* gates  = (short*)carve((size_t)BATCH * NGATES * 2);
    float* mid    = (float*)carve((size_t)BATCH * NP * 4);
    float* cell   = (float*)carve((size_t)BATCH * HID * 4);
    float* p_sum  = (float*)carve((size_t)BATCH * 4);
    int*   active = (int*)carve((size_t)BATCH * 4);

    pack_gates<<<(NGATES * KTOT + 255) / 256, 256, 0, stream>>>(
        Whi, Whf, Whc, Who, Wxi, Wxf, Wxc, Wxo,
        bxi, bhi, bxf, bhf, bxc, bhc, bxo, bho, Wg, bias_g);
    pack_P<<<(NP * HID + 255) / 256, 256, 0, stream>>>(W1, b1, W_halt, b_halt, P, bias_p);
    init_k<<<(BATCH * KTOT + 255) / 256, 256, 0, stream>>>(x, A, cell, p_sum, active, (float*)d_out);

    for (int t = 0; t < MAX_ITER; ++t) {
        gemm_act<<<dim3(NGATES / TN, BATCH / TM), 256, 0, stream>>>(
            A, KTOT, Wg, KTOT, bias_g, (void*)gates, NGATES, KTOT, 0);
        cell_update<<<(BATCH * HID) / 256, 256, 0, stream>>>(gates, cell, A, active);
        gemm_act<<<dim3(NP / TN, BATCH / TM), 256, 0, stream>>>(
            A, KTOT, P, HID, bias_p, (void*)mid, NP, HID, 1);
        finalize_k<<<BATCH / 4, 256, 0, stream>>>(mid, W2, b2, (float*)d_out, p_sum, active, t);
    }
}

// Round 2
// 1224.219 us; speedup vs baseline: 1.2104x; 1.2104x over previous
//
#include <hip/hip_runtime.h>
#include <hip/hip_bf16.h>

#define BATCH 8192
#define IN_DIM 64
#define HID 1024
#define KTOT 1088   // HID + IN_DIM, fused K
#define NGATES 4096 // 4*HID, column c = 64*G + 16*g + q -> gate g of h=16*G+q
#define OMID 128
#define NP 256      // padded mid cols (W1 rows 0..127, W_halt row 128, zeros)
#define MAX_ITER 8

#define TM 128
#define TN 128
#define TK 64

typedef __attribute__((ext_vector_type(8))) short short8;
typedef __attribute__((ext_vector_type(4))) float float4v;

__device__ __forceinline__ float bf2f(short s) {
    union { float f; unsigned u; } v; v.u = ((unsigned)(unsigned short)s) << 16; return v.f;
}
__device__ __forceinline__ short f2bf(float f) {
    union { float f; unsigned u; } v; v.f = f;
    unsigned r = v.u + 0x7fff + ((v.u >> 16) & 1);  // round-to-nearest-even
    return (short)(r >> 16);
}
__device__ __forceinline__ float sigmoidf_(float x) {
    float xc = fminf(fmaxf(x, -30.f), 30.f);
    return 1.f / (1.f + __expf(-xc));
}
__device__ __forceinline__ float tanhf_(float x) {
    float xc = fminf(fmaxf(x, -15.f), 15.f);
    float e = __expf(2.f * xc);
    return (e - 1.f) / (e + 1.f);
}

// C[M][N] = A[M][K] * B[N][K]^T  (+bias, fused epilogue)
// mode 0: LSTM gates — interleaved gate columns; epilogue does the full cell
//         update in-register: cell=f*cell+i*c, Aout.state=o*tanh(cell).
//         Inactive rows: copy old state A->Aout.
// mode 1: mid — fp32 out (ldc=NP), relu for col<128, sigmoid col==128, 0 else.
// LDS XOR swizzle: global chunk c of row rho lands at LDS chunk c^(rho&7),
// staged via per-lane source-chunk permutation so global_load_lds's
// contiguous-destination constraint is preserved. ds_read un-swizzles.
// Result: fragment reads rotate across all 32 banks (2-way, free) instead of
// 16-way conflicts on a 128B row stride.
__global__ __launch_bounds__(256) void gemm_fused(
    const short* __restrict__ A, int lda,
    const short* __restrict__ B, int ldb,
    const float* __restrict__ bias,
    int K, int mode,
    float* __restrict__ cell, short* __restrict__ Aout,
    const int* __restrict__ active,
    float* __restrict__ mid)
{
    __shared__ short As[TM * TK];
    __shared__ short Bs[TN * TK];
    const int tid  = threadIdx.x;
    const int wave = tid >> 6, lane = tid & 63;
    const int n0 = blockIdx.x * TN;
    const int m0 = blockIdx.y * TM;
    const int wm = wave & 1, wn = wave >> 1;

    float4v acc[4][4];
#pragma unroll
    for (int i = 0; i < 4; ++i)
#pragma unroll
        for (int j = 0; j < 4; ++j) acc[i][j] = (float4v)0.f;

    const int lrow8 = lane >> 3;                    // row within 8-row region
    const int lk    = (((lane & 7) ^ lrow8) * 8);   // swizzled source k-chunk

    for (int k0 = 0; k0 < K; k0 += TK) {
#pragma unroll
        for (int it = 0; it < 4; ++it) {
            const int rr = (wave * 4 + it) * 8;     // wave-uniform region row base
            const short* ga = A + (size_t)(m0 + rr + lrow8) * lda + k0 + lk;
            __builtin_amdgcn_global_load_lds(
                (const __attribute__((address_space(1))) void*)ga,
                (__attribute__((address_space(3))) void*)(As + rr * TK), 16, 0, 0);
            const short* gb = B + (size_t)(n0 + rr + lrow8) * ldb + k0 + lk;
            __builtin_amdgcn_global_load_lds(
                (const __attribute__((address_space(1))) void*)gb,
                (__attribute__((address_space(3))) void*)(Bs + rr * TK), 16, 0, 0);
        }
        __syncthreads();
#pragma unroll
        for (int kk = 0; kk < TK; kk += 32) {
            short8 af[4], bf[4];
#pragma unroll
            for (int i = 0; i < 4; ++i) {
                const int Ra = wm * 64 + i * 16 + (lane & 15);
                const int Rb = wn * 64 + i * 16 + (lane & 15);
                const int C  = (kk >> 3) + (lane >> 4);
                af[i] = *(const short8*)(As + Ra * TK + ((C ^ (Ra & 7)) << 3));
                bf[i] = *(const short8*)(Bs + Rb * TK + ((C ^ (Rb & 7)) << 3));
            }
#pragma unroll
            for (int i = 0; i < 4; ++i)
#pragma unroll
                for (int j = 0; j < 4; ++j)
                    acc[i][j] = __builtin_amdgcn_mfma_f32_16x16x32_bf16(af[i], bf[j], acc[i][j], 0, 0, 0);
        }
        __syncthreads();
    }

    const int colq = lane & 15;
    const int rowq = (lane >> 4) * 4;
    if (mode == 0) {
        const int G = blockIdx.x * 2 + wn;   // 64-col group = 16 hidden units
        const int h = G * 16 + colq;
        const float bi  = bias[G * 64 +  0 + colq];
        const float bff = bias[G * 64 + 16 + colq];
        const float bc  = bias[G * 64 + 32 + colq];
        const float bo  = bias[G * 64 + 48 + colq];
#pragma unroll
        for (int i = 0; i < 4; ++i) {
            const int rbase = m0 + wm * 64 + i * 16 + rowq;
#pragma unroll
            for (int r = 0; r < 4; ++r) {
                const int row = rbase + r;
                if (active[row]) {
                    const float ig = sigmoidf_(acc[i][0][r] + bi);
                    const float fg = sigmoidf_(acc[i][1][r] + bff);
                    const float cg = tanhf_(acc[i][2][r] + bc);
                    const float og = sigmoidf_(acc[i][3][r] + bo);
                    const size_t ci = (size_t)row * HID + h;
                    const float c = fg * cell[ci] + ig * cg;
                    cell[ci] = c;
                    Aout[(size_t)row * KTOT + h] = f2bf(og * tanhf_(c));
                } else {
                    Aout[(size_t)row * KTOT + h] = A[(size_t)row * lda + h];
                }
            }
        }
    } else {
        float* C = mid;
#pragma unroll
        for (int i = 0; i < 4; ++i) {
            const int rbase = m0 + wm * 64 + i * 16 + rowq;
#pragma unroll
            for (int j = 0; j < 4; ++j) {
                const int col = n0 + wn * 64 + j * 16 + colq;
                const float b = bias[col];
#pragma unroll
                for (int r = 0; r < 4; ++r) {
                    float v = acc[i][j][r] + b;
                    if (col < OMID) v = fmaxf(v, 0.f);
                    else if (col == OMID) v = sigmoidf_(v);
                    else v = 0.f;
                    C[(size_t)(rbase + r) * NP + col] = v;
                }
            }
        }
    }
}

// one wave per row: out = sigmoid(mid[0:128]·W2 + b2); halting bookkeeping
__global__ __launch_bounds__(256) void finalize_k(
    const float* __restrict__ mid, const float* __restrict__ W2, const float* __restrict__ b2,
    float* __restrict__ outp, float* __restrict__ p_sum, int* __restrict__ active, int t)
{
    const int wave = threadIdx.x >> 6, lane = threadIdx.x & 63;
    const int row = blockIdx.x * 4 + wave;
    if (!active[row]) return;
    const float* m = mid + (size_t)row * NP;
    float v = m[lane] * W2[lane] + m[lane + 64] * W2[lane + 64];
#pragma unroll
    for (int o = 32; o > 0; o >>= 1) v += __shfl_down(v, o);
    if (lane == 0) {
        const float ov = sigmoidf_(v + b2[0]);
        const float h  = m[OMID];
        const float p  = p_sum[row];
        const float pn = p + h;
        const bool fin = (pn >= 1.f - 1e-3f) || (t == MAX_ITER - 1);
        const float halt = fin ? (1.f - p) : h;
        outp[row] += ov * halt;
        p_sum[row] = fin ? 1.f : pn;
        if (fin) active[row] = 0;
    }
}

__global__ __launch_bounds__(256) void pack_gates(
    const float* __restrict__ Whi, const float* __restrict__ Whf,
    const float* __restrict__ Whc, const float* __restrict__ Who,
    const float* __restrict__ Wxi, const float* __restrict__ Wxf,
    const float* __restrict__ Wxc, const float* __restrict__ Wxo,
    const float* __restrict__ bxi, const float* __restrict__ bhi,
    const float* __restrict__ bxf, const float* __restrict__ bhf,
    const float* __restrict__ bxc, const float* __restrict__ bhc,
    const float* __restrict__ bxo, const float* __restrict__ bho,
    short* __restrict__ Wg, float* __restrict__ bias_g)
{
    const int idx = blockIdx.x * 256 + threadIdx.x;  // over NGATES*KTOT
    if (idx >= NGATES * KTOT) return;
    const int n = idx / KTOT, k = idx - n * KTOT;
    // interleaved layout: n = 64*G + 16*g + q  ->  gate g of hidden h=16*G+q
    const int G = n >> 6, g = (n >> 4) & 3, q = n & 15;
    const int h = G * 16 + q;
    const float* Wh = (g == 0) ? Whi : (g == 1) ? Whf : (g == 2) ? Whc : Who;
    const float* Wx = (g == 0) ? Wxi : (g == 1) ? Wxf : (g == 2) ? Wxc : Wxo;
    const float v = (k < HID) ? Wh[h * HID + k] : Wx[h * IN_DIM + (k - HID)];
    Wg[idx] = f2bf(v);
    if (k == 0) {
        const float* bx = (g == 0) ? bxi : (g == 1) ? bxf : (g == 2) ? bxc : bxo;
        const float* bh = (g == 0) ? bhi : (g == 1) ? bhf : (g == 2) ? bhc : bho;
        bias_g[n] = bx[h] + bh[h];
    }
}

__global__ __launch_bounds__(256) void pack_P(
    const float* __restrict__ W1, const float* __restrict__ b1,
    const float* __restrict__ W_halt, const float* __restrict__ b_halt,
    short* __restrict__ P, float* __restrict__ bias_p)
{
    const int idx = blockIdx.x * 256 + threadIdx.x;  // over NP*HID
    if (idx >= NP * HID) return;
    const int n = idx >> 10, k = idx & 1023;
    const float v = (n < OMID) ? W1[n * HID + k] : (n == OMID ? W_halt[k] : 0.f);
    P[idx] = f2bf(v);
    if (k == 0) bias_p[n] = (n < OMID) ? b1[n] : (n == OMID ? b_halt[0] : 0.f);
}

__global__ __launch_bounds__(256) void init_k(
    const float* __restrict__ x, short* __restrict__ A0, short* __restrict__ A1,
    float* __restrict__ cell, float* __restrict__ p_sum, int* __restrict__ active,
    float* __restrict__ outp)
{
    const int idx = blockIdx.x * 256 + threadIdx.x;  // over BATCH*KTOT
    if (idx >= BATCH * KTOT) return;
    const int row = idx / KTOT, k = idx - row * KTOT;
    const short v = (k < HID) ? (short)0 : f2bf(x[row * IN_DIM + (k - HID)]);
    A0[idx] = v;
    A1[idx] = v;   // x columns iteration-invariant; state part overwritten each step
    if (k < HID) cell[(size_t)row * HID + k] = 0.f;
    if (k == 0) { p_sum[row] = 0.f; active[row] = 1; outp[row] = 0.f; }
}

extern "C" void kernel_launch(void* const* d_in, const int* in_sizes, int n_in,
                              void* d_out, int out_size, void* d_ws, size_t ws_size,
                              hipStream_t stream) {
    const float* x    = (const float*)d_in[0];
    const float* Wxi  = (const float*)d_in[1];
    const float* bxi  = (const float*)d_in[2];
    const float* Whi  = (const float*)d_in[3];
    const float* bhi  = (const float*)d_in[4];
    const float* Wxf  = (const float*)d_in[5];
    const float* bxf  = (const float*)d_in[6];
    const float* Whf  = (const float*)d_in[7];
    const float* bhf  = (const float*)d_in[8];
    const float* Wxc  = (const float*)d_in[9];
    const float* bxc  = (const float*)d_in[10];
    const float* Whc  = (const float*)d_in[11];
    const float* bhc  = (const float*)d_in[12];
    const float* Wxo  = (const float*)d_in[13];
    const float* bxo  = (const float*)d_in[14];
    const float* Who  = (const float*)d_in[15];
    const float* bho  = (const float*)d_in[16];
    const float* W_halt = (const float*)d_in[17];
    const float* b_halt = (const float*)d_in[18];
    const float* W1   = (const float*)d_in[19];
    const float* b1   = (const float*)d_in[20];
    const float* W2   = (const float*)d_in[21];
    const float* b2   = (const float*)d_in[22];

    char* p = (char*)d_ws;
    auto carve = [&](size_t bytes) { char* r = p; p += (bytes + 255) & ~(size_t)255; return r; };
    short* A0     = (short*)carve((size_t)BATCH * KTOT * 2);
    short* A1     = (short*)carve((size_t)BATCH * KTOT * 2);
    short* Wg     = (short*)carve((size_t)NGATES * KTOT * 2);
    float* bias_g = (float*)carve((size_t)NGATES * 4);
    short* P      = (short*)carve((size_t)NP * HID * 2);
    float* bias_p = (float*)carve((size_t)NP * 4);
    float* mid    = (float*)carve((size_t)BATCH * NP * 4);
    float* cell   = (float*)carve((size_t)BATCH * HID * 4);
    float* p_sum  = (float*)carve((size_t)BATCH * 4);
    int*   active = (int*)carve((size_t)BATCH * 4);

    pack_gates<<<(NGATES * KTOT + 255) / 256, 256, 0, stream>>>(
        Whi, Whf, Whc, Who, Wxi, Wxf, Wxc, Wxo,
        bxi, bhi, bxf, bhf, bxc, bhc, bxo, bho, Wg, bias_g);
    pack_P<<<(NP * HID + 255) / 256, 256, 0, stream>>>(W1, b1, W_halt, b_halt, P, bias_p);
    init_k<<<(BATCH * KTOT + 255) / 256, 256, 0, stream>>>(x, A0, A1, cell, p_sum, active, (float*)d_out);

    for (int t = 0; t < MAX_ITER; ++t) {
        const short* Ain = (t & 1) ? A1 : A0;
        short*       Aot = (t & 1) ? A0 : A1;
        gemm_fused<<<dim3(NGATES / TN, BATCH / TM), 256, 0, stream>>>(
            Ain, KTOT, Wg, KTOT, bias_g, KTOT, 0, cell, Aot, active, nullptr);
        gemm_fused<<<dim3(NP / TN, BATCH / TM), 256, 0, stream>>>(
            Aot, KTOT, P, HID, bias_p, HID, 1, nullptr, nullptr, active, mid);
        finalize_k<<<BATCH / 4, 256, 0, stream>>>(mid, W2, b2, (float*)d_out, p_sum, active, t);
    }
}

// Round 3
// 713.595 us; speedup vs baseline: 2.0766x; 1.7156x over previous
//
#include <hip/hip_runtime.h>
#include <hip/hip_bf16.h>

#define BATCH 8192
#define IN_DIM 64
#define HID 1024
#define KTOT 1088   // HID + IN_DIM, fused K
#define NGATES 4096 // 4*HID, column c = 64*G + 16*g + q -> gate g of h=16*G+q
#define OMID 128
#define NP 256      // padded mid cols (W1 rows 0..127, W_halt row 128, zeros)
#define MAX_ITER 8

#define TM 128
#define TN 128
#define TK 64

typedef __attribute__((ext_vector_type(8))) short short8;
typedef __attribute__((ext_vector_type(4))) float float4v;

__device__ __forceinline__ float bf2f(short s) {
    union { float f; unsigned u; } v; v.u = ((unsigned)(unsigned short)s) << 16; return v.f;
}
__device__ __forceinline__ short f2bf(float f) {
    union { float f; unsigned u; } v; v.f = f;
    unsigned r = v.u + 0x7fff + ((v.u >> 16) & 1);  // round-to-nearest-even
    return (short)(r >> 16);
}
__device__ __forceinline__ float sigmoidf_(float x) {
    float xc = fminf(fmaxf(x, -30.f), 30.f);
    return 1.f / (1.f + __expf(-xc));
}
__device__ __forceinline__ float tanhf_(float x) {
    float xc = fminf(fmaxf(x, -15.f), 15.f);
    float e = __expf(2.f * xc);
    return (e - 1.f) / (e + 1.f);
}

// C[pos][N] = A[ridx[pos]][K] * B[N][K]^T (+bias, fused epilogue), rows
// indirected through the compacted active-row list; blocks beyond cnt[t]
// early-exit (data-dependent, graph-capture-safe — grid shape fixed).
// mode 0: LSTM gates — interleaved gate columns; epilogue does the full cell
//         update in-register: cell=f*cell+i*c, Aout[row].state=o*tanh(cell).
// mode 1: mid — fp32 out at compacted pos (ldc=NP), relu col<128, sigmoid
//         col==128, 0 else.
// LDS XOR swizzle (verified R2: SQ_LDS_BANK_CONFLICT -> 0): global chunk c of
// row rho lands at LDS chunk c^(rho&7) via per-lane source permutation,
// preserving global_load_lds's contiguous-destination constraint.
__global__ __launch_bounds__(256) void gemm_fused(
    const short* __restrict__ A, int lda,
    const short* __restrict__ B, int ldb,
    const float* __restrict__ bias,
    int K, int mode,
    float* __restrict__ cell, short* __restrict__ Aout,
    const int* __restrict__ ridx, const int* __restrict__ cnt, int t,
    float* __restrict__ mid)
{
    __shared__ short As[TM * TK];
    __shared__ short Bs[TN * TK];
    const int m0 = blockIdx.y * TM;
    const int n_act = cnt[t];
    if (m0 >= n_act) return;                 // compaction early-exit
    const int tid  = threadIdx.x;
    const int wave = tid >> 6, lane = tid & 63;
    const int n0 = blockIdx.x * TN;
    const int wm = wave & 1, wn = wave >> 1;

    float4v acc[4][4];
#pragma unroll
    for (int i = 0; i < 4; ++i)
#pragma unroll
        for (int j = 0; j < 4; ++j) acc[i][j] = (float4v)0.f;

    const int lrow8 = lane >> 3;                    // row within 8-row region
    const int lk    = (((lane & 7) ^ lrow8) * 8);   // swizzled source k-chunk
    // indirected A row for this lane's staging (entries beyond n_act are
    // valid in-range indices -> harmless dummy reads)
    const size_t arow = (size_t)ridx[m0 + (wave * 4) * 8 + 0 * 8 + lrow8];
    int arows[4];
#pragma unroll
    for (int it = 0; it < 4; ++it)
        arows[it] = ridx[m0 + (wave * 4 + it) * 8 + lrow8];
    (void)arow;

    for (int k0 = 0; k0 < K; k0 += TK) {
#pragma unroll
        for (int it = 0; it < 4; ++it) {
            const int rr = (wave * 4 + it) * 8;     // wave-uniform region row base
            const short* ga = A + (size_t)arows[it] * lda + k0 + lk;
            __builtin_amdgcn_global_load_lds(
                (const __attribute__((address_space(1))) void*)ga,
                (__attribute__((address_space(3))) void*)(As + rr * TK), 16, 0, 0);
            const short* gb = B + (size_t)(n0 + rr + lrow8) * ldb + k0 + lk;
            __builtin_amdgcn_global_load_lds(
                (const __attribute__((address_space(1))) void*)gb,
                (__attribute__((address_space(3))) void*)(Bs + rr * TK), 16, 0, 0);
        }
        __syncthreads();
#pragma unroll
        for (int kk = 0; kk < TK; kk += 32) {
            short8 af[4], bf[4];
#pragma unroll
            for (int i = 0; i < 4; ++i) {
                const int Ra = wm * 64 + i * 16 + (lane & 15);
                const int Rb = wn * 64 + i * 16 + (lane & 15);
                const int C  = (kk >> 3) + (lane >> 4);
                af[i] = *(const short8*)(As + Ra * TK + ((C ^ (Ra & 7)) << 3));
                bf[i] = *(const short8*)(Bs + Rb * TK + ((C ^ (Rb & 7)) << 3));
            }
#pragma unroll
            for (int i = 0; i < 4; ++i)
#pragma unroll
                for (int j = 0; j < 4; ++j)
                    acc[i][j] = __builtin_amdgcn_mfma_f32_16x16x32_bf16(af[i], bf[j], acc[i][j], 0, 0, 0);
        }
        __syncthreads();
    }

    const int colq = lane & 15;
    const int rowq = (lane >> 4) * 4;
    if (mode == 0) {
        const int G = blockIdx.x * 2 + wn;   // 64-col group = 16 hidden units
        const int h = G * 16 + colq;
        const float bi  = bias[G * 64 +  0 + colq];
        const float bff = bias[G * 64 + 16 + colq];
        const float bc  = bias[G * 64 + 32 + colq];
        const float bo  = bias[G * 64 + 48 + colq];
#pragma unroll
        for (int i = 0; i < 4; ++i) {
            const int pbase = m0 + wm * 64 + i * 16 + rowq;
#pragma unroll
            for (int r = 0; r < 4; ++r) {
                const int pos = pbase + r;
                if (pos < n_act) {
                    const int row = ridx[pos];
                    const float ig = sigmoidf_(acc[i][0][r] + bi);
                    const float fg = sigmoidf_(acc[i][1][r] + bff);
                    const float cg = tanhf_(acc[i][2][r] + bc);
                    const float og = sigmoidf_(acc[i][3][r] + bo);
                    const size_t ci = (size_t)row * HID + h;
                    const float c = fg * cell[ci] + ig * cg;
                    cell[ci] = c;
                    Aout[(size_t)row * KTOT + h] = f2bf(og * tanhf_(c));
                }
            }
        }
    } else {
#pragma unroll
        for (int i = 0; i < 4; ++i) {
            const int pbase = m0 + wm * 64 + i * 16 + rowq;
#pragma unroll
            for (int j = 0; j < 4; ++j) {
                const int col = n0 + wn * 64 + j * 16 + colq;
                const float b = bias[col];
#pragma unroll
                for (int r = 0; r < 4; ++r) {
                    float v = acc[i][j][r] + b;
                    if (col < OMID) v = fmaxf(v, 0.f);
                    else if (col == OMID) v = sigmoidf_(v);
                    else v = 0.f;
                    mid[(size_t)(pbase + r) * NP + col] = v;  // compacted pos
                }
            }
        }
    }
}

// one wave per compacted pos: out = sigmoid(mid[0:128]·W2 + b2); halting
// bookkeeping + append survivors to next step's compacted list.
__global__ __launch_bounds__(256) void finalize_k(
    const float* __restrict__ mid, const float* __restrict__ W2, const float* __restrict__ b2,
    float* __restrict__ outp, float* __restrict__ p_sum,
    const int* __restrict__ ridx_cur, int* __restrict__ ridx_next,
    int* __restrict__ cnt, int t)
{
    const int wave = threadIdx.x >> 6, lane = threadIdx.x & 63;
    const int pos = blockIdx.x * 4 + wave;
    if (pos >= cnt[t]) return;
    const int row = ridx_cur[pos];
    const float* m = mid + (size_t)pos * NP;
    float v = m[lane] * W2[lane] + m[lane + 64] * W2[lane + 64];
#pragma unroll
    for (int o = 32; o > 0; o >>= 1) v += __shfl_down(v, o);
    if (lane == 0) {
        const float ov = sigmoidf_(v + b2[0]);
        const float h  = m[OMID];
        const float p  = p_sum[row];
        const float pn = p + h;
        const bool fin = (pn >= 1.f - 1e-3f) || (t == MAX_ITER - 1);
        const float halt = fin ? (1.f - p) : h;
        outp[row] += ov * halt;
        p_sum[row] = fin ? 1.f : pn;
        if (!fin) {
            const int d = atomicAdd(&cnt[t + 1], 1);
            ridx_next[d] = row;
        }
    }
}

__global__ __launch_bounds__(256) void pack_gates(
    const float* __restrict__ Whi, const float* __restrict__ Whf,
    const float* __restrict__ Whc, const float* __restrict__ Who,
    const float* __restrict__ Wxi, const float* __restrict__ Wxf,
    const float* __restrict__ Wxc, const float* __restrict__ Wxo,
    const float* __restrict__ bxi, const float* __restrict__ bhi,
    const float* __restrict__ bxf, const float* __restrict__ bhf,
    const float* __restrict__ bxc, const float* __restrict__ bhc,
    const float* __restrict__ bxo, const float* __restrict__ bho,
    short* __restrict__ Wg, float* __restrict__ bias_g)
{
    const int idx = blockIdx.x * 256 + threadIdx.x;  // over NGATES*KTOT
    if (idx >= NGATES * KTOT) return;
    const int n = idx / KTOT, k = idx - n * KTOT;
    // interleaved layout: n = 64*G + 16*g + q  ->  gate g of hidden h=16*G+q
    const int G = n >> 6, g = (n >> 4) & 3, q = n & 15;
    const int h = G * 16 + q;
    const float* Wh = (g == 0) ? Whi : (g == 1) ? Whf : (g == 2) ? Whc : Who;
    const float* Wx = (g == 0) ? Wxi : (g == 1) ? Wxf : (g == 2) ? Wxc : Wxo;
    const float v = (k < HID) ? Wh[h * HID + k] : Wx[h * IN_DIM + (k - HID)];
    Wg[idx] = f2bf(v);
    if (k == 0) {
        const float* bx = (g == 0) ? bxi : (g == 1) ? bxf : (g == 2) ? bxc : bxo;
        const float* bh = (g == 0) ? bhi : (g == 1) ? bhf : (g == 2) ? bhc : bho;
        bias_g[n] = bx[h] + bh[h];
    }
}

__global__ __launch_bounds__(256) void pack_P(
    const float* __restrict__ W1, const float* __restrict__ b1,
    const float* __restrict__ W_halt, const float* __restrict__ b_halt,
    short* __restrict__ P, float* __restrict__ bias_p)
{
    const int idx = blockIdx.x * 256 + threadIdx.x;  // over NP*HID
    if (idx >= NP * HID) return;
    const int n = idx >> 10, k = idx & 1023;
    const float v = (n < OMID) ? W1[n * HID + k] : (n == OMID ? W_halt[k] : 0.f);
    P[idx] = f2bf(v);
    if (k == 0) bias_p[n] = (n < OMID) ? b1[n] : (n == OMID ? b_halt[0] : 0.f);
}

__global__ __launch_bounds__(256) void init_k(
    const float* __restrict__ x, short* __restrict__ A0, short* __restrict__ A1,
    float* __restrict__ cell, float* __restrict__ p_sum,
    int* __restrict__ ridx0, int* __restrict__ ridx1, int* __restrict__ cnt,
    float* __restrict__ outp)
{
    const int idx = blockIdx.x * 256 + threadIdx.x;  // over BATCH*KTOT
    if (idx >= BATCH * KTOT) return;
    const int row = idx / KTOT, k = idx - row * KTOT;
    const short v = (k < HID) ? (short)0 : f2bf(x[row * IN_DIM + (k - HID)]);
    A0[idx] = v;
    A1[idx] = v;   // x columns iteration-invariant; state part overwritten each step
    if (k < HID) cell[(size_t)row * HID + k] = 0.f;
    if (k == 0) {
        p_sum[row] = 0.f;
        outp[row] = 0.f;
        ridx0[row] = row;   // step 0: identity compaction
        ridx1[row] = 0;     // valid in-range dummies for padded tile reads
    }
    if (row == 0 && k <= MAX_ITER) cnt[k] = (k == 0) ? BATCH : 0;
}

extern "C" void kernel_launch(void* const* d_in, const int* in_sizes, int n_in,
                              void* d_out, int out_size, void* d_ws, size_t ws_size,
                              hipStream_t stream) {
    const float* x    = (const float*)d_in[0];
    const float* Wxi  = (const float*)d_in[1];
    const float* bxi  = (const float*)d_in[2];
    const float* Whi  = (const float*)d_in[3];
    const float* bhi  = (const float*)d_in[4];
    const float* Wxf  = (const float*)d_in[5];
    const float* bxf  = (const float*)d_in[6];
    const float* Whf  = (const float*)d_in[7];
    const float* bhf  = (const float*)d_in[8];
    const float* Wxc  = (const float*)d_in[9];
    const float* bxc  = (const float*)d_in[10];
    const float* Whc  = (const float*)d_in[11];
    const float* bhc  = (const float*)d_in[12];
    const float* Wxo  = (const float*)d_in[13];
    const float* bxo  = (const float*)d_in[14];
    const float* Who  = (const float*)d_in[15];
    const float* bho  = (const float*)d_in[16];
    const float* W_halt = (const float*)d_in[17];
    const float* b_halt = (const float*)d_in[18];
    const float* W1   = (const float*)d_in[19];
    const float* b1   = (const float*)d_in[20];
    const float* W2   = (const float*)d_in[21];
    const float* b2   = (const float*)d_in[22];

    char* p = (char*)d_ws;
    auto carve = [&](size_t bytes) { char* r = p; p += (bytes + 255) & ~(size_t)255; return r; };
    short* A0     = (short*)carve((size_t)BATCH * KTOT * 2);
    short* A1     = (short*)carve((size_t)BATCH * KTOT * 2);
    short* Wg     = (short*)carve((size_t)NGATES * KTOT * 2);
    float* bias_g = (float*)carve((size_t)NGATES * 4);
    short* P      = (short*)carve((size_t)NP * HID * 2);
    float* bias_p = (float*)carve((size_t)NP * 4);
    float* mid    = (float*)carve((size_t)BATCH * NP * 4);
    float* cell   = (float*)carve((size_t)BATCH * HID * 4);
    float* p_sum  = (float*)carve((size_t)BATCH * 4);
    int*   ridx0  = (int*)carve((size_t)BATCH * 4);
    int*   ridx1  = (int*)carve((size_t)BATCH * 4);
    int*   cnt    = (int*)carve((size_t)(MAX_ITER + 1) * 4);

    pack_gates<<<(NGATES * KTOT + 255) / 256, 256, 0, stream>>>(
        Whi, Whf, Whc, Who, Wxi, Wxf, Wxc, Wxo,
        bxi, bhi, bxf, bhf, bxc, bhc, bxo, bho, Wg, bias_g);
    pack_P<<<(NP * HID + 255) / 256, 256, 0, stream>>>(W1, b1, W_halt, b_halt, P, bias_p);
    init_k<<<(BATCH * KTOT + 255) / 256, 256, 0, stream>>>(
        x, A0, A1, cell, p_sum, ridx0, ridx1, cnt, (float*)d_out);

    for (int t = 0; t < MAX_ITER; ++t) {
        const short* Ain = (t & 1) ? A1 : A0;
        short*       Aot = (t & 1) ? A0 : A1;
        const int* rc = (t & 1) ? ridx1 : ridx0;
        int*       rn = (t & 1) ? ridx0 : ridx1;
        gemm_fused<<<dim3(NGATES / TN, BATCH / TM), 256, 0, stream>>>(
            Ain, KTOT, Wg, KTOT, bias_g, KTOT, 0, cell, Aot, rc, cnt, t, nullptr);
        gemm_fused<<<dim3(NP / TN, BATCH / TM), 256, 0, stream>>>(
            Aot, KTOT, P, HID, bias_p, HID, 1, nullptr, nullptr, rc, cnt, t, mid);
        finalize_k<<<BATCH / 4, 256, 0, stream>>>(
            mid, W2, b2, (float*)d_out, p_sum, rc, rn, cnt, t);
    }
}

// Round 4
// 636.135 us; speedup vs baseline: 2.3294x; 1.1218x over previous
//
#include <hip/hip_runtime.h>
#include <hip/hip_bf16.h>

#define BATCH 8192
#define IN_DIM 64
#define HID 1024
#define KTOT 1088   // HID + IN_DIM, fused K
#define NGATES 4096 // 4*HID, column c = 64*G + 16*g + q -> gate g of h=16*G+q
#define OMID 128
#define NP 256      // padded mid cols (W1 rows 0..127, W_halt row 128, zeros)
#define MAX_ITER 8

#define TM 128
#define TN 128
#define TK 64

typedef __attribute__((ext_vector_type(8))) short short8;
typedef __attribute__((ext_vector_type(4))) float float4v;

__device__ __forceinline__ float bf2f(short s) {
    union { float f; unsigned u; } v; v.u = ((unsigned)(unsigned short)s) << 16; return v.f;
}
__device__ __forceinline__ short f2bf(float f) {
    union { float f; unsigned u; } v; v.f = f;
    unsigned r = v.u + 0x7fff + ((v.u >> 16) & 1);  // round-to-nearest-even
    return (short)(r >> 16);
}
__device__ __forceinline__ float sigmoidf_(float x) {
    float xc = fminf(fmaxf(x, -30.f), 30.f);
    return 1.f / (1.f + __expf(-xc));
}
__device__ __forceinline__ float tanhf_(float x) {
    float xc = fminf(fmaxf(x, -15.f), 15.f);
    float e = __expf(2.f * xc);
    return (e - 1.f) / (e + 1.f);
}

// C[pos][N] = A[ridx[pos]][K] * B[N][K]^T (+bias, fused epilogue), rows
// indirected through the compacted active-row list; blocks beyond cnt[t]
// early-exit (data-dependent, graph-capture-safe — grid shape fixed).
// mode 0: LSTM gates — interleaved gate columns; epilogue does the full cell
//         update in-register: cell=f*cell+i*c, Aout[row].state=o*tanh(cell).
//         t=0 special case (launched by host): A,B offset by HID and K=64 —
//         state is zero so only the x-part of the fused K contributes.
// mode 1: mid — fp32 out at compacted pos (ldc=NP), relu col<128, sigmoid
//         col==128, 0 else.
// LDS XOR swizzle (verified R2: SQ_LDS_BANK_CONFLICT -> 0): global chunk c of
// row rho lands at LDS chunk c^(rho&7) via per-lane source permutation,
// preserving global_load_lds's contiguous-destination constraint.
__global__ __launch_bounds__(256) void gemm_fused(
    const short* __restrict__ A, int lda,
    const short* __restrict__ B, int ldb,
    const float* __restrict__ bias,
    int K, int mode,
    float* __restrict__ cell, short* __restrict__ Aout,
    const int* __restrict__ ridx, const int* __restrict__ cnt, int t,
    float* __restrict__ mid)
{
    __shared__ short As[TM * TK];
    __shared__ short Bs[TN * TK];
    const int m0 = blockIdx.y * TM;
    const int n_act = cnt[t];
    if (m0 >= n_act) return;                 // compaction early-exit
    const int tid  = threadIdx.x;
    const int wave = tid >> 6, lane = tid & 63;
    const int n0 = blockIdx.x * TN;
    const int wm = wave & 1, wn = wave >> 1;

    float4v acc[4][4];
#pragma unroll
    for (int i = 0; i < 4; ++i)
#pragma unroll
        for (int j = 0; j < 4; ++j) acc[i][j] = (float4v)0.f;

    const int lrow8 = lane >> 3;                    // row within 8-row region
    const int lk    = (((lane & 7) ^ lrow8) * 8);   // swizzled source k-chunk
    // indirected A row for this lane's staging (entries beyond n_act are
    // valid in-range indices -> harmless dummy reads)
    int arows[4];
#pragma unroll
    for (int it = 0; it < 4; ++it)
        arows[it] = ridx[m0 + (wave * 4 + it) * 8 + lrow8];

    for (int k0 = 0; k0 < K; k0 += TK) {
#pragma unroll
        for (int it = 0; it < 4; ++it) {
            const int rr = (wave * 4 + it) * 8;     // wave-uniform region row base
            const short* ga = A + (size_t)arows[it] * lda + k0 + lk;
            __builtin_amdgcn_global_load_lds(
                (const __attribute__((address_space(1))) void*)ga,
                (__attribute__((address_space(3))) void*)(As + rr * TK), 16, 0, 0);
            const short* gb = B + (size_t)(n0 + rr + lrow8) * ldb + k0 + lk;
            __builtin_amdgcn_global_load_lds(
                (const __attribute__((address_space(1))) void*)gb,
                (__attribute__((address_space(3))) void*)(Bs + rr * TK), 16, 0, 0);
        }
        __syncthreads();
#pragma unroll
        for (int kk = 0; kk < TK; kk += 32) {
            short8 af[4], bf[4];
#pragma unroll
            for (int i = 0; i < 4; ++i) {
                const int Ra = wm * 64 + i * 16 + (lane & 15);
                const int Rb = wn * 64 + i * 16 + (lane & 15);
                const int C  = (kk >> 3) + (lane >> 4);
                af[i] = *(const short8*)(As + Ra * TK + ((C ^ (Ra & 7)) << 3));
                bf[i] = *(const short8*)(Bs + Rb * TK + ((C ^ (Rb & 7)) << 3));
            }
#pragma unroll
            for (int i = 0; i < 4; ++i)
#pragma unroll
                for (int j = 0; j < 4; ++j)
                    acc[i][j] = __builtin_amdgcn_mfma_f32_16x16x32_bf16(af[i], bf[j], acc[i][j], 0, 0, 0);
        }
        __syncthreads();
    }

    const int colq = lane & 15;
    const int rowq = (lane >> 4) * 4;
    if (mode == 0) {
        const int G = blockIdx.x * 2 + wn;   // 64-col group = 16 hidden units
        const int h = G * 16 + colq;
        const float bi  = bias[G * 64 +  0 + colq];
        const float bff = bias[G * 64 + 16 + colq];
        const float bc  = bias[G * 64 + 32 + colq];
        const float bo  = bias[G * 64 + 48 + colq];
#pragma unroll
        for (int i = 0; i < 4; ++i) {
            const int pbase = m0 + wm * 64 + i * 16 + rowq;
#pragma unroll
            for (int r = 0; r < 4; ++r) {
                const int pos = pbase + r;
                if (pos < n_act) {
                    const int row = ridx[pos];
                    const float ig = sigmoidf_(acc[i][0][r] + bi);
                    const float fg = sigmoidf_(acc[i][1][r] + bff);
                    const float cg = tanhf_(acc[i][2][r] + bc);
                    const float og = sigmoidf_(acc[i][3][r] + bo);
                    const size_t ci = (size_t)row * HID + h;
                    const float c = fg * cell[ci] + ig * cg;
                    cell[ci] = c;
                    Aout[(size_t)row * KTOT + h] = f2bf(og * tanhf_(c));
                }
            }
        }
    } else {
#pragma unroll
        for (int i = 0; i < 4; ++i) {
            const int pbase = m0 + wm * 64 + i * 16 + rowq;
#pragma unroll
            for (int j = 0; j < 4; ++j) {
                const int col = n0 + wn * 64 + j * 16 + colq;
                const float b = bias[col];
#pragma unroll
                for (int r = 0; r < 4; ++r) {
                    float v = acc[i][j][r] + b;
                    if (col < OMID) v = fmaxf(v, 0.f);
                    else if (col == OMID) v = sigmoidf_(v);
                    else v = 0.f;
                    mid[(size_t)(pbase + r) * NP + col] = v;  // compacted pos
                }
            }
        }
    }
}

// one wave per compacted pos: out = sigmoid(mid[0:128]·W2 + b2); halting
// bookkeeping + append survivors to next step's compacted list.
__global__ __launch_bounds__(256) void finalize_k(
    const float* __restrict__ mid, const float* __restrict__ W2, const float* __restrict__ b2,
    float* __restrict__ outp, float* __restrict__ p_sum,
    const int* __restrict__ ridx_cur, int* __restrict__ ridx_next,
    int* __restrict__ cnt, int t)
{
    const int wave = threadIdx.x >> 6, lane = threadIdx.x & 63;
    const int pos = blockIdx.x * 4 + wave;
    if (pos >= cnt[t]) return;
    const int row = ridx_cur[pos];
    const float* m = mid + (size_t)pos * NP;
    float v = m[lane] * W2[lane] + m[lane + 64] * W2[lane + 64];
#pragma unroll
    for (int o = 32; o > 0; o >>= 1) v += __shfl_down(v, o);
    if (lane == 0) {
        const float ov = sigmoidf_(v + b2[0]);
        const float h  = m[OMID];
        const float p  = p_sum[row];
        const float pn = p + h;
        const bool fin = (pn >= 1.f - 1e-3f) || (t == MAX_ITER - 1);
        const float halt = fin ? (1.f - p) : h;
        outp[row] += ov * halt;
        p_sum[row] = fin ? 1.f : pn;
        if (!fin) {
            const int d = atomicAdd(&cnt[t + 1], 1);
            ridx_next[d] = row;
        }
    }
}

// one dispatch for all setup: weight packing + A/cell/bookkeeping init
#define SETUP_INIT  (BATCH * KTOT)
#define SETUP_WG    (NGATES * KTOT)
#define SETUP_P     (NP * HID)
#define SETUP_TOT   (SETUP_INIT + SETUP_WG + SETUP_P)
__global__ __launch_bounds__(256) void setup_k(
    const float* __restrict__ x,
    const float* __restrict__ Whi, const float* __restrict__ Whf,
    const float* __restrict__ Whc, const float* __restrict__ Who,
    const float* __restrict__ Wxi, const float* __restrict__ Wxf,
    const float* __restrict__ Wxc, const float* __restrict__ Wxo,
    const float* __restrict__ bxi, const float* __restrict__ bhi,
    const float* __restrict__ bxf, const float* __restrict__ bhf,
    const float* __restrict__ bxc, const float* __restrict__ bhc,
    const float* __restrict__ bxo, const float* __restrict__ bho,
    const float* __restrict__ W1, const float* __restrict__ b1,
    const float* __restrict__ W_halt, const float* __restrict__ b_halt,
    short* __restrict__ A0, short* __restrict__ A1,
    float* __restrict__ cell, float* __restrict__ p_sum,
    int* __restrict__ ridx0, int* __restrict__ ridx1, int* __restrict__ cnt,
    float* __restrict__ outp,
    short* __restrict__ Wg, float* __restrict__ bias_g,
    short* __restrict__ P, float* __restrict__ bias_p)
{
    int idx = blockIdx.x * 256 + threadIdx.x;
    if (idx < SETUP_INIT) {
        const int row = idx / KTOT, k = idx - row * KTOT;
        const short v = (k < HID) ? (short)0 : f2bf(x[row * IN_DIM + (k - HID)]);
        A0[idx] = v;
        A1[idx] = v;   // x cols iteration-invariant; state part overwritten each step
        if (k < HID) cell[(size_t)row * HID + k] = 0.f;
        if (k == 0) {
            p_sum[row] = 0.f;
            outp[row] = 0.f;
            ridx0[row] = row;   // step 0: identity compaction
            ridx1[row] = 0;     // in-range dummies for padded tile reads
        }
        if (row == 0 && k <= MAX_ITER) cnt[k] = (k == 0) ? BATCH : 0;
        return;
    }
    idx -= SETUP_INIT;
    if (idx < SETUP_WG) {
        const int n = idx / KTOT, k = idx - n * KTOT;
        // interleaved layout: n = 64*G + 16*g + q  ->  gate g of hidden h=16*G+q
        const int G = n >> 6, g = (n >> 4) & 3, q = n & 15;
        const int h = G * 16 + q;
        const float* Wh = (g == 0) ? Whi : (g == 1) ? Whf : (g == 2) ? Whc : Who;
        const float* Wx = (g == 0) ? Wxi : (g == 1) ? Wxf : (g == 2) ? Wxc : Wxo;
        const float v = (k < HID) ? Wh[h * HID + k] : Wx[h * IN_DIM + (k - HID)];
        Wg[idx] = f2bf(v);
        if (k == 0) {
            const float* bx = (g == 0) ? bxi : (g == 1) ? bxf : (g == 2) ? bxc : bxo;
            const float* bh = (g == 0) ? bhi : (g == 1) ? bhf : (g == 2) ? bhc : bho;
            bias_g[n] = bx[h] + bh[h];
        }
        return;
    }
    idx -= SETUP_WG;
    if (idx < SETUP_P) {
        const int n = idx >> 10, k = idx & 1023;
        const float v = (n < OMID) ? W1[n * HID + k] : (n == OMID ? W_halt[k] : 0.f);
        P[idx] = f2bf(v);
        if (k == 0) bias_p[n] = (n < OMID) ? b1[n] : (n == OMID ? b_halt[0] : 0.f);
    }
}

extern "C" void kernel_launch(void* const* d_in, const int* in_sizes, int n_in,
                              void* d_out, int out_size, void* d_ws, size_t ws_size,
                              hipStream_t stream) {
    const float* x    = (const float*)d_in[0];
    const float* Wxi  = (const float*)d_in[1];
    const float* bxi  = (const float*)d_in[2];
    const float* Whi  = (const float*)d_in[3];
    const float* bhi  = (const float*)d_in[4];
    const float* Wxf  = (const float*)d_in[5];
    const float* bxf  = (const float*)d_in[6];
    const float* Whf  = (const float*)d_in[7];
    const float* bhf  = (const float*)d_in[8];
    const float* Wxc  = (const float*)d_in[9];
    const float* bxc  = (const float*)d_in[10];
    const float* Whc  = (const float*)d_in[11];
    const float* bhc  = (const float*)d_in[12];
    const float* Wxo  = (const float*)d_in[13];
    const float* bxo  = (const float*)d_in[14];
    const float* Who  = (const float*)d_in[15];
    const float* bho  = (const float*)d_in[16];
    const float* W_halt = (const float*)d_in[17];
    const float* b_halt = (const float*)d_in[18];
    const float* W1   = (const float*)d_in[19];
    const float* b1   = (const float*)d_in[20];
    const float* W2   = (const float*)d_in[21];
    const float* b2   = (const float*)d_in[22];

    char* p = (char*)d_ws;
    auto carve = [&](size_t bytes) { char* r = p; p += (bytes + 255) & ~(size_t)255; return r; };
    short* A0     = (short*)carve((size_t)BATCH * KTOT * 2);
    short* A1     = (short*)carve((size_t)BATCH * KTOT * 2);
    short* Wg     = (short*)carve((size_t)NGATES * KTOT * 2);
    float* bias_g = (float*)carve((size_t)NGATES * 4);
    short* P      = (short*)carve((size_t)NP * HID * 2);
    float* bias_p = (float*)carve((size_t)NP * 4);
    float* mid    = (float*)carve((size_t)BATCH * NP * 4);
    float* cell   = (float*)carve((size_t)BATCH * HID * 4);
    float* p_sum  = (float*)carve((size_t)BATCH * 4);
    int*   ridx0  = (int*)carve((size_t)BATCH * 4);
    int*   ridx1  = (int*)carve((size_t)BATCH * 4);
    int*   cnt    = (int*)carve((size_t)(MAX_ITER + 1) * 4);

    setup_k<<<(SETUP_TOT + 255) / 256, 256, 0, stream>>>(
        x, Whi, Whf, Whc, Who, Wxi, Wxf, Wxc, Wxo,
        bxi, bhi, bxf, bhf, bxc, bhc, bxo, bho,
        W1, b1, W_halt, b_halt,
        A0, A1, cell, p_sum, ridx0, ridx1, cnt, (float*)d_out,
        Wg, bias_g, P, bias_p);

    for (int t = 0; t < MAX_ITER; ++t) {
        const short* Ain = (t & 1) ? A1 : A0;
        short*       Aot = (t & 1) ? A0 : A1;
        const int* rc = (t & 1) ? ridx1 : ridx0;
        int*       rn = (t & 1) ? ridx0 : ridx1;
        if (t == 0) {
            // state==0: only the x-part (K=64) of the fused K contributes.
            gemm_fused<<<dim3(NGATES / TN, BATCH / TM), 256, 0, stream>>>(
                Ain + HID, KTOT, Wg + HID, KTOT, bias_g, IN_DIM, 0,
                cell, Aot, rc, cnt, t, nullptr);
        } else {
            gemm_fused<<<dim3(NGATES / TN, BATCH / TM), 256, 0, stream>>>(
                Ain, KTOT, Wg, KTOT, bias_g, KTOT, 0, cell, Aot, rc, cnt, t, nullptr);
        }
        gemm_fused<<<dim3(NP / TN, BATCH / TM), 256, 0, stream>>>(
            Aot, KTOT, P, HID, bias_p, HID, 1, nullptr, nullptr, rc, cnt, t, mid);
        finalize_k<<<BATCH / 4, 256, 0, stream>>>(
            mid, W2, b2, (float*)d_out, p_sum, rc, rn, cnt, t);
    }
}